// Round 1
// baseline (592.412 us; speedup 1.0000x reference)
//
#include <hip/hip_runtime.h>

// LogicGatedSNN: fused single-pass kernel.
// One block per output row (8192 blocks x 256 threads).
// Phase 1: current[row] = sum_i (syn[row,i] > 50) * x[i]   (float4 loads)
// Phase 2: per-row LIF scalars (spike, membrane, refractory)
// Phase 3: trace row update: clip(trace*0.8 + spike*x, 0, 5) (float4 R/W)
// x (32 KB) staged in LDS once, reused by both passes.
// Memory-bound: ~768 MB HBM traffic -> ~122 us floor at 6.3 TB/s.

#define IN_F 8192
#define OUT_F 8192
#define BLOCK 256
#define VEC_ITERS (IN_F / 4 / BLOCK)  // 8

__global__ __launch_bounds__(BLOCK) void snn_fused_kernel(
    const float* __restrict__ x_in,    // spike_input       [IN_F]
    const float* __restrict__ syn,     // synapse_states    [OUT_F, IN_F]
    const float* __restrict__ mem,     // membrane_potential[OUT_F]
    const float* __restrict__ thr,     // adaptive_threshold[OUT_F]
    const float* __restrict__ trace,   // eligibility_trace [OUT_F, IN_F]
    const float* __restrict__ refr,    // refractory_period [OUT_F]
    float* __restrict__ out_spikes,    // [OUT_F]
    float* __restrict__ out_mem,       // [OUT_F]
    float* __restrict__ out_trace,     // [OUT_F, IN_F]
    float* __restrict__ out_refr)      // [OUT_F]
{
    const int row = blockIdx.x;
    const int tid = threadIdx.x;

    __shared__ float4 sx[IN_F / 4];          // 32 KB: x staged once
    __shared__ float s_partial[BLOCK / 64];  // per-wave partials

    const float4* __restrict__ x4 = (const float4*)x_in;
    const float4* __restrict__ syn4 =
        (const float4*)(syn + (size_t)row * IN_F);

    // Stage x into LDS (also used by phase 3).
    #pragma unroll
    for (int it = 0; it < VEC_ITERS; ++it) {
        sx[it * BLOCK + tid] = x4[it * BLOCK + tid];
    }
    __syncthreads();

    // Phase 1: row reduction. w = (syn > 50), current = dot(w, x).
    float acc = 0.0f;
    #pragma unroll
    for (int it = 0; it < VEC_ITERS; ++it) {
        const int idx = it * BLOCK + tid;
        const float4 s = syn4[idx];
        const float4 xv = sx[idx];
        acc += (s.x > 50.0f) ? xv.x : 0.0f;
        acc += (s.y > 50.0f) ? xv.y : 0.0f;
        acc += (s.z > 50.0f) ? xv.z : 0.0f;
        acc += (s.w > 50.0f) ? xv.w : 0.0f;
    }
    // Wave (64-lane) butterfly reduce, then cross-wave via LDS.
    #pragma unroll
    for (int off = 32; off > 0; off >>= 1) {
        acc += __shfl_down(acc, off, 64);
    }
    if ((tid & 63) == 0) s_partial[tid >> 6] = acc;
    __syncthreads();

    const float current =
        s_partial[0] + s_partial[1] + s_partial[2] + s_partial[3];

    // Phase 2: per-row LIF scalars (computed redundantly by all threads;
    // stored by thread 0).
    const float r = refr[row];
    const float v = mem[row] * 0.5f + current * (1.0f - r * 0.5f);
    const float spike = (v >= thr[row]) ? 1.0f : 0.0f;
    if (tid == 0) {
        out_spikes[row] = spike;
        out_mem[row] = v * (1.0f - spike);
        out_refr[row] = fminf(fmaxf(r + spike - 0.1f, 0.0f), 1.0f);
    }

    // Phase 3: trace row update.
    const float4* __restrict__ tr4 =
        (const float4*)(trace + (size_t)row * IN_F);
    float4* __restrict__ otr4 = (float4*)(out_trace + (size_t)row * IN_F);
    #pragma unroll
    for (int it = 0; it < VEC_ITERS; ++it) {
        const int idx = it * BLOCK + tid;
        const float4 t = tr4[idx];
        const float4 xv = sx[idx];
        float4 o;
        o.x = fminf(fmaxf(t.x * 0.8f + spike * xv.x, 0.0f), 5.0f);
        o.y = fminf(fmaxf(t.y * 0.8f + spike * xv.y, 0.0f), 5.0f);
        o.z = fminf(fmaxf(t.z * 0.8f + spike * xv.z, 0.0f), 5.0f);
        o.w = fminf(fmaxf(t.w * 0.8f + spike * xv.w, 0.0f), 5.0f);
        otr4[idx] = o;
    }
}

extern "C" void kernel_launch(void* const* d_in, const int* in_sizes, int n_in,
                              void* d_out, int out_size, void* d_ws, size_t ws_size,
                              hipStream_t stream) {
    const float* x_in  = (const float*)d_in[0];  // spike_input
    const float* syn   = (const float*)d_in[1];  // synapse_states
    const float* mem   = (const float*)d_in[2];  // membrane_potential
    const float* thr   = (const float*)d_in[3];  // adaptive_threshold
    const float* trace = (const float*)d_in[4];  // eligibility_trace
    const float* refr  = (const float*)d_in[5];  // refractory_period

    float* out = (float*)d_out;
    float* out_spikes = out;                                  // [8192]
    float* out_mem    = out + OUT_F;                          // [8192]
    float* out_trace  = out + 2 * OUT_F;                      // [8192*8192]
    float* out_refr   = out + 2 * OUT_F + (size_t)OUT_F * IN_F;  // [8192]

    snn_fused_kernel<<<OUT_F, BLOCK, 0, stream>>>(
        x_in, syn, mem, thr, trace, refr,
        out_spikes, out_mem, out_trace, out_refr);
}

// Round 2
// 587.242 us; speedup vs baseline: 1.0088x; 1.0088x over previous
//
#include <hip/hip_runtime.h>

// LogicGatedSNN: split two-kernel version.
//
// R0 post-mortem: fused one-block-per-row kernel hit only 2.75 TB/s (34%).
// Cause: 32.5 KB LDS -> 38% occupancy, and two barrier-separated phases
// serialized syn-read -> reduce -> trace-read per block. Fusion saves zero
// HBM bytes here, so split into two pure streamers:
//   A: binarized matvec + LIF scalars. One WAVE per row, no LDS, no barrier.
//   B: trace update. One block per row, float4 read-modify-write stream.
// x (32 KB) lives in L1 (exactly L1-sized) for both kernels.

#define IN_F 8192
#define OUT_F 8192
#define BLOCK 256

// ---------------- Kernel A: current = (syn>50)@x, then LIF ----------------
// grid = OUT_F/4 blocks of 256 threads; each 64-lane wave owns one row.
__global__ __launch_bounds__(BLOCK) void snn_matvec_kernel(
    const float4* __restrict__ x4,     // spike_input as float4 [IN_F/4]
    const float* __restrict__ syn,     // synapse_states [OUT_F, IN_F]
    const float* __restrict__ mem,     // membrane_potential [OUT_F]
    const float* __restrict__ thr,     // adaptive_threshold [OUT_F]
    const float* __restrict__ refr,    // refractory_period [OUT_F]
    float* __restrict__ out_spikes,
    float* __restrict__ out_mem,
    float* __restrict__ out_refr)
{
    const int wave = threadIdx.x >> 6;          // 0..3
    const int lane = threadIdx.x & 63;
    const int row  = (blockIdx.x << 2) + wave;

    const float4* __restrict__ syn4 =
        (const float4*)(syn + (size_t)row * IN_F);

    float acc = 0.0f;
    #pragma unroll 8
    for (int it = 0; it < IN_F / 4 / 64; ++it) {    // 32 iterations
        const int idx = (it << 6) + lane;
        const float4 s  = syn4[idx];
        const float4 xv = x4[idx];
        acc += (s.x > 50.0f) ? xv.x : 0.0f;
        acc += (s.y > 50.0f) ? xv.y : 0.0f;
        acc += (s.z > 50.0f) ? xv.z : 0.0f;
        acc += (s.w > 50.0f) ? xv.w : 0.0f;
    }
    // 64-lane butterfly reduction (wave-local, no LDS needed).
    #pragma unroll
    for (int off = 32; off > 0; off >>= 1) {
        acc += __shfl_down(acc, off, 64);
    }
    if (lane == 0) {
        const float r = refr[row];
        const float v = mem[row] * 0.5f + acc * (1.0f - r * 0.5f);
        const float spike = (v >= thr[row]) ? 1.0f : 0.0f;
        out_spikes[row] = spike;
        out_mem[row]    = v * (1.0f - spike);
        out_refr[row]   = fminf(fmaxf(r + spike - 0.1f, 0.0f), 1.0f);
    }
}

// ---------------- Kernel B: trace = clip(trace*0.8 + spike*x, 0, 5) -------
// grid = OUT_F blocks; block b streams row b (8 float4 per thread).
__global__ __launch_bounds__(BLOCK) void snn_trace_kernel(
    const float4* __restrict__ x4,      // [IN_F/4]
    const float4* __restrict__ tr4,     // eligibility_trace [OUT_F * IN_F/4]
    const float* __restrict__ spikes,   // [OUT_F] (from kernel A)
    float4* __restrict__ otr4)          // out_trace [OUT_F * IN_F/4]
{
    const int row = blockIdx.x;
    const float spike = spikes[row];    // wave-uniform broadcast load
    const size_t base = (size_t)row * (IN_F / 4);

    #pragma unroll
    for (int it = 0; it < IN_F / 4 / BLOCK; ++it) {   // 8 iterations
        const int idx = it * BLOCK + threadIdx.x;
        const float4 t  = tr4[base + idx];
        const float4 xv = x4[idx];
        float4 o;
        o.x = fminf(fmaxf(t.x * 0.8f + spike * xv.x, 0.0f), 5.0f);
        o.y = fminf(fmaxf(t.y * 0.8f + spike * xv.y, 0.0f), 5.0f);
        o.z = fminf(fmaxf(t.z * 0.8f + spike * xv.z, 0.0f), 5.0f);
        o.w = fminf(fmaxf(t.w * 0.8f + spike * xv.w, 0.0f), 5.0f);
        otr4[base + idx] = o;
    }
}

extern "C" void kernel_launch(void* const* d_in, const int* in_sizes, int n_in,
                              void* d_out, int out_size, void* d_ws, size_t ws_size,
                              hipStream_t stream) {
    const float* x_in  = (const float*)d_in[0];  // spike_input
    const float* syn   = (const float*)d_in[1];  // synapse_states
    const float* mem   = (const float*)d_in[2];  // membrane_potential
    const float* thr   = (const float*)d_in[3];  // adaptive_threshold
    const float* trace = (const float*)d_in[4];  // eligibility_trace
    const float* refr  = (const float*)d_in[5];  // refractory_period

    float* out = (float*)d_out;
    float* out_spikes = out;                                     // [8192]
    float* out_mem    = out + OUT_F;                             // [8192]
    float* out_trace  = out + 2 * OUT_F;                         // [8192^2]
    float* out_refr   = out + 2 * OUT_F + (size_t)OUT_F * IN_F;  // [8192]

    snn_matvec_kernel<<<OUT_F / 4, BLOCK, 0, stream>>>(
        (const float4*)x_in, syn, mem, thr, refr,
        out_spikes, out_mem, out_refr);

    snn_trace_kernel<<<OUT_F, BLOCK, 0, stream>>>(
        (const float4*)x_in, (const float4*)trace, out_spikes,
        (float4*)out_trace);
}